// Round 2
// baseline (3242.826 us; speedup 1.0000x reference)
//
#include <hip/hip_runtime.h>
#include <hip/hip_bf16.h>

// GConvLSTM single step x4 layers, H=C=0 => f-gate dead, peepholes dead.
//   1. deg/dinv + CSR(dst) build
//   2. per layer: T_k via SpMV recursion (stored); ONE fused GEMM over
//      [N, K*Fin] @ [K*Fin, 3F] with gate nonlinearity epilogue -> H
//   3. final 152->2 linear + softmax
// Storage type ST (fp32 or bf16) chosen at runtime from ws_size; accumulation
// always fp32. No silent early-return: if ws is too small we fault visibly.

#define IN_CH 10

// ---------------- storage converters ----------------
__device__ __forceinline__ float ldv(const float* p) { return *p; }
__device__ __forceinline__ float ldv(const __hip_bfloat16* p) { return __bfloat162float(*p); }
__device__ __forceinline__ void stv(float* p, float v) { *p = v; }
__device__ __forceinline__ void stv(__hip_bfloat16* p, float v) { *p = __float2bfloat16(v); }

// ---------------- graph preprocessing ----------------

__global__ void k_count(const int* __restrict__ dst, int* __restrict__ cnt, int e) {
    int i = blockIdx.x * 256 + threadIdx.x;
    if (i < e) atomicAdd(&cnt[dst[i]], 1);
}

__global__ void k_dinv(const int* __restrict__ cnt, float* __restrict__ dinv, int n) {
    int i = blockIdx.x * 256 + threadIdx.x;
    if (i < n) dinv[i] = cnt[i] > 0 ? rsqrtf((float)cnt[i]) : 0.f;
}

__global__ __launch_bounds__(1024) void k_scan(const int* __restrict__ cnt,
                                               int* __restrict__ row_ptr, int n) {
    __shared__ int sums[1024];
    int t = threadIdx.x;
    int chunk = (n + 1023) >> 10;
    int lo = t * chunk;
    int hi = lo + chunk < n ? lo + chunk : n;
    int s = 0;
    for (int i = lo; i < hi; i++) s += cnt[i];
    sums[t] = s;
    __syncthreads();
    for (int off = 1; off < 1024; off <<= 1) {
        int v = (t >= off) ? sums[t - off] : 0;
        __syncthreads();
        sums[t] += v;
        __syncthreads();
    }
    int prefix = (t == 0) ? 0 : sums[t - 1];
    for (int i = lo; i < hi; i++) { row_ptr[i] = prefix; prefix += cnt[i]; }
    if (t == 0) row_ptr[n] = sums[1023];
}

__global__ void k_copy_i32(const int* __restrict__ a, int* __restrict__ b, int n) {
    int i = blockIdx.x * 256 + threadIdx.x;
    if (i < n) b[i] = a[i];
}

__global__ void k_fill(const int* __restrict__ src, const int* __restrict__ dst,
                       const float* __restrict__ dinv, int* __restrict__ cursor,
                       int* __restrict__ csr_src, float* __restrict__ csr_w, int e) {
    int i = blockIdx.x * 256 + threadIdx.x;
    if (i >= e) return;
    int s = src[i], d = dst[i];
    int pos = atomicAdd(&cursor[d], 1);
    csr_src[pos] = s;
    csr_w[pos] = dinv[s] * dinv[d];
}

// ---------------- Cheb SpMV (gather form) ----------------
// Tout[n,f] = -scale * sum_e w[e]*X[src[e],f]  - (Tprev ? Tprev[n,f] : 0)

template <typename ST, int F, int FP>
__global__ void k_spmv(const ST* __restrict__ X, const ST* __restrict__ Tprev,
                       ST* __restrict__ Tout, const int* __restrict__ row_ptr,
                       const int* __restrict__ csr_src, const float* __restrict__ csr_w,
                       int n, float scale) {
    int f = threadIdx.x;
    int node = blockIdx.x * blockDim.y + threadIdx.y;
    if (node >= n) return;
    if (f >= F) return;
    int lo = row_ptr[node], hi = row_ptr[node + 1];
    float acc = 0.f;
    for (int e = lo; e < hi; e++) {
        acc = fmaf(csr_w[e], ldv(&X[(size_t)csr_src[e] * F + f]), acc);
    }
    float v = -scale * acc - (Tprev ? ldv(&Tprev[(size_t)node * F + f]) : 0.f);
    stv(&Tout[(size_t)node * F + f], v);
}

// ---------------- fused multi-T GEMM + gate epilogue ----------------
// Virtual A = [T_0 | ... | T_{K-1}]  (N x K*FIN), W packed [K*FIN][f*4+g]
// (g: 0=i,1=c,2=o,3=pad). Block: 64 rows x 32 f-cols; 256 thr = 32 fx * 8 ry,
// each thread: 8 rows x 3 gates. Epilogue: h = relu(sig(o)*tanh(sig(i)*tanh(c))).

struct TP { const void* p[5]; };

template <typename ST, int FIN, int K>
__global__ __launch_bounds__(256) void k_chebgate(TP tp, const float* __restrict__ Wp,
                                                  const float* __restrict__ b4,
                                                  ST* __restrict__ H, int n, int F,
                                                  int F4pad) {
    __shared__ float As[FIN][68];   // transposed A tile, stride 68 (16B-aligned rows)
    __shared__ float Ws[FIN][128];  // 32 f * 4 gates
    const int tid = threadIdx.x;
    const int fx = tid & 31, ry = tid >> 5;
    const int row0 = blockIdx.y * 64;
    const int f0 = blockIdx.x * 32;
    const int f = f0 + fx;

    float acc[8][3];
    const float4 bv = *(const float4*)&b4[(size_t)f * 4];
#pragma unroll
    for (int r = 0; r < 8; r++) { acc[r][0] = bv.x; acc[r][1] = bv.y; acc[r][2] = bv.z; }

#pragma unroll
    for (int t = 0; t < K; t++) {
        const ST* T = (const ST*)tp.p[t];
        for (int idx = tid; idx < 64 * FIN; idx += 256) {
            int r = idx / FIN, a = idx - r * FIN;
            int rr = row0 + r;
            if (rr >= n) rr = n - 1;
            As[a][r] = ldv(&T[(size_t)rr * FIN + a]);
        }
        const float* Wt = Wp + (size_t)t * FIN * F4pad + (size_t)f0 * 4;
        for (int idx = tid; idx < FIN * 128; idx += 256) {
            int aa = idx >> 7, c = idx & 127;
            Ws[aa][c] = Wt[(size_t)aa * F4pad + c];
        }
        __syncthreads();
#pragma unroll 2
        for (int a = 0; a < FIN; a++) {
            const float4 w = *(const float4*)&Ws[a][fx * 4];
            const float4 x0 = *(const float4*)&As[a][ry * 8];
            const float4 x1 = *(const float4*)&As[a][ry * 8 + 4];
            const float xr[8] = {x0.x, x0.y, x0.z, x0.w, x1.x, x1.y, x1.z, x1.w};
#pragma unroll
            for (int r = 0; r < 8; r++) {
                acc[r][0] = fmaf(xr[r], w.x, acc[r][0]);
                acc[r][1] = fmaf(xr[r], w.y, acc[r][1]);
                acc[r][2] = fmaf(xr[r], w.z, acc[r][2]);
            }
        }
        __syncthreads();
    }

    if (f < F) {
#pragma unroll
        for (int r = 0; r < 8; r++) {
            int row = row0 + ry * 8 + r;
            if (row < n) {
                float gi = 1.f / (1.f + expf(-acc[r][0]));
                float go = 1.f / (1.f + expf(-acc[r][2]));
                float c = gi * tanhf(acc[r][1]);
                float h = go * tanhf(c);
                stv(&H[(size_t)row * F + f], fmaxf(h, 0.f));
            }
        }
    }
}

// ---------------- weight/bias packing (gate-interleaved, padded) ----------------
// Wp[(k*FIN+a)*F4pad + f*4 + g] = Wg[k][a][f] for g<3 && f<F else 0.

__global__ void k_pack_w(const float* __restrict__ Wi, const float* __restrict__ Wc,
                         const float* __restrict__ Wo, float* __restrict__ Wp,
                         int KFIN, int F, int F4pad) {
    int idx = blockIdx.x * 256 + threadIdx.x;
    int tot = KFIN * F4pad;
    if (idx >= tot) return;
    int c = idx % F4pad;
    int ka = idx / F4pad;
    int f = c >> 2, g = c & 3;
    float v = 0.f;
    if (g < 3 && f < F) {
        const float* Wg = (g == 0) ? Wi : ((g == 1) ? Wc : Wo);
        v = Wg[(size_t)ka * F + f];
    }
    Wp[idx] = v;
}

__global__ void k_pack_b(const float* __restrict__ bxi, const float* __restrict__ bhi,
                         const float* __restrict__ bi, const float* __restrict__ bxc,
                         const float* __restrict__ bhc, const float* __restrict__ bc,
                         const float* __restrict__ bxo, const float* __restrict__ bho,
                         const float* __restrict__ bo, float* __restrict__ b4,
                         int F, int F4pad) {
    int idx = blockIdx.x * 256 + threadIdx.x;
    if (idx >= F4pad) return;
    int f = idx >> 2, g = idx & 3;
    float v = 0.f;
    if (g < 3 && f < F) {
        if (g == 0) v = bxi[f] + bhi[f] + bi[f];
        else if (g == 1) v = bxc[f] + bhc[f] + bc[f];
        else v = bxo[f] + bho[f] + bo[f];
    }
    b4[idx] = v;
}

// ---------------- fp32 -> bf16 convert (bf16 path only) ----------------
__global__ void k_cvt(const float* __restrict__ x, __hip_bfloat16* __restrict__ y, int n) {
    int i = blockIdx.x * 256 + threadIdx.x;
    if (i < n) y[i] = __float2bfloat16(x[i]);
}

// ---------------- final linear + softmax ----------------
template <typename ST>
__global__ void k_final(const ST* __restrict__ H, const float* __restrict__ W,
                        const float* __restrict__ b, float* __restrict__ out, int n) {
    int gtid = blockIdx.x * blockDim.x + threadIdx.x;
    int node = gtid >> 6;
    int lane = threadIdx.x & 63;
    if (node >= n) return;
    const ST* h = H + (size_t)node * 152;
    float l0 = 0.f, l1 = 0.f;
    for (int f = lane; f < 152; f += 64) {
        float hv = ldv(&h[f]);
        l0 = fmaf(hv, W[f * 2 + 0], l0);
        l1 = fmaf(hv, W[f * 2 + 1], l1);
    }
#pragma unroll
    for (int off = 32; off > 0; off >>= 1) {
        l0 += __shfl_down(l0, off);
        l1 += __shfl_down(l1, off);
    }
    if (lane == 0) {
        l0 += b[0];
        l1 += b[1];
        float m = fmaxf(l0, l1);
        float e0 = __expf(l0 - m), e1 = __expf(l1 - m);
        float s = 1.f / (e0 + e1);
        out[(size_t)node * 2 + 0] = e0 * s;
        out[(size_t)node * 2 + 1] = e1 * s;
    }
}

// ---------------- workspace layout (single source of truth) ----------------

struct Bufs {
    int* row_ptr;
    int* cnt;  // doubles as cursor after dinv
    float* dinv;
    int* csr_src;
    float* csr_w;
    char* T[4];
    char* Ha;
    char* Hb;
    char* Xc;
    float* Wp;
    float* b4;
};

static size_t ws_layout(char* base, int N, int E, size_t e, Bufs* b) {
    size_t off = 0;
    auto carve = [&](size_t bytes) -> char* {
        char* r = base ? base + off : nullptr;
        off = (off + bytes + 255) & ~(size_t)255;
        return r;
    };
    Bufs t;
    t.row_ptr = (int*)carve((size_t)(N + 1) * 4);
    t.cnt     = (int*)carve((size_t)N * 4);
    t.dinv    = (float*)carve((size_t)N * 4);
    t.csr_src = (int*)carve((size_t)E * 4);
    t.csr_w   = (float*)carve((size_t)E * 4);
    for (int i = 0; i < 4; i++) t.T[i] = carve((size_t)N * 64 * e);
    t.Ha = carve((size_t)N * 64 * e);
    t.Hb = carve((size_t)N * 152 * e);
    t.Xc = carve((size_t)N * IN_CH * e);
    t.Wp = (float*)carve((size_t)320 * 640 * 4);
    t.b4 = (float*)carve((size_t)640 * 4);
    if (b) *b = t;
    return off;
}

// ---------------- templated pipeline ----------------

template <typename ST>
static void launch_spmv(int F, const ST* X, const ST* Tprev, ST* Tout, const int* rp,
                        const int* cs, const float* cw, int n, float scale, hipStream_t s) {
    switch (F) {
        case 10: { dim3 b(16, 16); k_spmv<ST, 10, 16><<<(n + 15) / 16, b, 0, s>>>(X, Tprev, Tout, rp, cs, cw, n, scale); break; }
        case 16: { dim3 b(16, 16); k_spmv<ST, 16, 16><<<(n + 15) / 16, b, 0, s>>>(X, Tprev, Tout, rp, cs, cw, n, scale); break; }
        case 32: { dim3 b(32, 8);  k_spmv<ST, 32, 32><<<(n + 7) / 8, b, 0, s>>>(X, Tprev, Tout, rp, cs, cw, n, scale); break; }
        case 64: { dim3 b(64, 4);  k_spmv<ST, 64, 64><<<(n + 3) / 4, b, 0, s>>>(X, Tprev, Tout, rp, cs, cw, n, scale); break; }
    }
}

template <typename ST>
static void run_all(const float* X0, void* const* d_in, char* wsbase, int N, int E,
                    float* out, hipStream_t stream) {
    Bufs B;
    ws_layout(wsbase, N, E, sizeof(ST), &B);
    const int* ei = (const int*)d_in[1];
    const int* src = ei;
    const int* dst = ei + E;

    int gE = (E + 255) / 256, gN = (N + 255) / 256;
    hipMemsetAsync(B.cnt, 0, (size_t)N * 4, stream);
    k_count<<<gE, 256, 0, stream>>>(dst, B.cnt, E);
    k_dinv<<<gN, 256, 0, stream>>>(B.cnt, B.dinv, N);
    k_scan<<<1, 1024, 0, stream>>>(B.cnt, B.row_ptr, N);
    k_copy_i32<<<gN, 256, 0, stream>>>(B.row_ptr, B.cnt, N);  // cnt := cursor
    k_fill<<<gE, 256, 0, stream>>>(src, dst, B.dinv, B.cnt, B.csr_src, B.csr_w, E);

    // layer 0 input
    const ST* Xin;
    if constexpr (sizeof(ST) == 2) {
        k_cvt<<<(N * IN_CH + 255) / 256, 256, 0, stream>>>(X0, (__hip_bfloat16*)B.Xc, N * IN_CH);
        Xin = (const ST*)B.Xc;
    } else {
        Xin = (const ST*)X0;
    }

    struct LayerCfg { int K, Fin, F, Ftiles, base; };
    const LayerCfg L[4] = {{2, 10, 16, 1, 2}, {3, 16, 32, 1, 18}, {4, 32, 64, 2, 34}, {5, 64, 152, 5, 50}};

    for (int li = 0; li < 4; li++) {
        const LayerCfg& c = L[li];
        int K = c.K, Fin = c.Fin, F = c.F;
        int F4pad = c.Ftiles * 128;
        const float* Wi = (const float*)d_in[c.base + 0];
        const float* Wc = (const float*)d_in[c.base + 8];
        const float* Wo = (const float*)d_in[c.base + 12];

        int wtot = K * Fin * F4pad;
        k_pack_w<<<(wtot + 255) / 256, 256, 0, stream>>>(Wi, Wc, Wo, B.Wp, K * Fin, F, F4pad);
        k_pack_b<<<(F4pad + 255) / 256, 256, 0, stream>>>(
            (const float*)d_in[c.base + 1], (const float*)d_in[c.base + 2],
            (const float*)d_in[c.base + 3], (const float*)d_in[c.base + 9],
            (const float*)d_in[c.base + 10], (const float*)d_in[c.base + 11],
            (const float*)d_in[c.base + 13], (const float*)d_in[c.base + 14],
            (const float*)d_in[c.base + 15], B.b4, F, F4pad);

        // Chebyshev T_k chain
        TP tp;
        tp.p[0] = Xin;
        const ST* Tkm1 = Xin;
        const ST* Tkm2 = nullptr;
        for (int k = 1; k < K; k++) {
            ST* outb = (ST*)B.T[k - 1];
            launch_spmv<ST>(Fin, Tkm1, (k >= 2) ? Tkm2 : (const ST*)nullptr, outb,
                            B.row_ptr, B.csr_src, B.csr_w, N, (k == 1) ? 1.f : 2.f, stream);
            tp.p[k] = outb;
            Tkm2 = Tkm1;
            Tkm1 = outb;
        }

        ST* Hout = (ST*)((li & 1) ? B.Hb : B.Ha);
        dim3 grid(c.Ftiles, (N + 63) / 64);
        switch (li) {
            case 0: k_chebgate<ST, 10, 2><<<grid, 256, 0, stream>>>(tp, B.Wp, B.b4, Hout, N, F, F4pad); break;
            case 1: k_chebgate<ST, 16, 3><<<grid, 256, 0, stream>>>(tp, B.Wp, B.b4, Hout, N, F, F4pad); break;
            case 2: k_chebgate<ST, 32, 4><<<grid, 256, 0, stream>>>(tp, B.Wp, B.b4, Hout, N, F, F4pad); break;
            case 3: k_chebgate<ST, 64, 5><<<grid, 256, 0, stream>>>(tp, B.Wp, B.b4, Hout, N, F, F4pad); break;
        }
        Xin = Hout;
    }

    const float* linW = (const float*)d_in[66];
    const float* linb = (const float*)d_in[67];
    int totThreads = N * 64;
    k_final<ST><<<(totThreads + 255) / 256, 256, 0, stream>>>(Xin, linW, linb, out, N);
}

extern "C" void kernel_launch(void* const* d_in, const int* in_sizes, int n_in,
                              void* d_out, int out_size, void* d_ws, size_t ws_size,
                              hipStream_t stream) {
    const float* X0 = (const float*)d_in[0];
    const int N = in_sizes[0] / IN_CH;
    const int E = in_sizes[1] / 2;

    size_t need_f32 = ws_layout(nullptr, N, E, 4, nullptr);
    size_t need_b16 = ws_layout(nullptr, N, E, 2, nullptr);

    // Prefer fp32 accuracy; fall back to bf16 storage if ws is tight.
    // If even bf16 doesn't fit, run fp32 anyway -> faults visibly (never a
    // silent zero output).
    if (ws_size >= need_f32 || ws_size < need_b16) {
        run_all<float>(X0, d_in, (char*)d_ws, N, E, (float*)d_out, stream);
    } else {
        run_all<__hip_bfloat16>(X0, d_in, (char*)d_ws, N, E, (float*)d_out, stream);
    }
}

// Round 3
// 2078.454 us; speedup vs baseline: 1.5602x; 1.5602x over previous
//
#include <hip/hip_runtime.h>

// GConvLSTM single step x4 layers, H=C=0 => f-gate dead, peepholes dead.
// bf16 storage everywhere (harness compares in bf16 space, thr 1e-2).
//   - SpMV: bf16x2 gather, fp32 accumulate
//   - L0/L1 chebgate: VALU (tiny)
//   - L2/L3 chebgate: MFMA bf16 16x16x32, no LDS (A-frags direct from global,
//     B = weights L2-resident), gate epilogue fused
// Workspace ~122 MB with manual region overlap (fits proven 124 MB bound).

#define IN_CH 10
typedef unsigned short u16;
typedef short bf16x8 __attribute__((ext_vector_type(8)));
typedef float f32x4 __attribute__((ext_vector_type(4)));

__device__ __forceinline__ float bf2f(u16 u) { return __uint_as_float(((unsigned)u) << 16); }
__device__ __forceinline__ u16 f2bf(float f) {
    unsigned x = __float_as_uint(f);
    return (u16)((x + 0x7fff + ((x >> 16) & 1)) >> 16);  // RNE
}

// ---------------- storage converters (templated kernels) ----------------
__device__ __forceinline__ float ldv(const float* p) { return *p; }
__device__ __forceinline__ float ldv(const u16* p) { return bf2f(*p); }
__device__ __forceinline__ void stv(float* p, float v) { *p = v; }
__device__ __forceinline__ void stv(u16* p, float v) { *p = f2bf(v); }

// ---------------- graph preprocessing ----------------

__global__ void k_count(const int* __restrict__ dst, int* __restrict__ cnt, int e) {
    int i = blockIdx.x * 256 + threadIdx.x;
    if (i < e) atomicAdd(&cnt[dst[i]], 1);
}

__global__ void k_dinv(const int* __restrict__ cnt, float* __restrict__ dinv, int n) {
    int i = blockIdx.x * 256 + threadIdx.x;
    if (i < n) dinv[i] = cnt[i] > 0 ? rsqrtf((float)cnt[i]) : 0.f;
}

__global__ __launch_bounds__(1024) void k_scan(const int* __restrict__ cnt,
                                               int* __restrict__ row_ptr, int n) {
    __shared__ int sums[1024];
    int t = threadIdx.x;
    int chunk = (n + 1023) >> 10;
    int lo = t * chunk;
    int hi = lo + chunk < n ? lo + chunk : n;
    int s = 0;
    for (int i = lo; i < hi; i++) s += cnt[i];
    sums[t] = s;
    __syncthreads();
    for (int off = 1; off < 1024; off <<= 1) {
        int v = (t >= off) ? sums[t - off] : 0;
        __syncthreads();
        sums[t] += v;
        __syncthreads();
    }
    int prefix = (t == 0) ? 0 : sums[t - 1];
    for (int i = lo; i < hi; i++) { row_ptr[i] = prefix; prefix += cnt[i]; }
    if (t == 0) row_ptr[n] = sums[1023];
}

__global__ void k_copy_i32(const int* __restrict__ a, int* __restrict__ b, int n) {
    int i = blockIdx.x * 256 + threadIdx.x;
    if (i < n) b[i] = a[i];
}

__global__ void k_fill(const int* __restrict__ src, const int* __restrict__ dst,
                       const float* __restrict__ dinv, int* __restrict__ cursor,
                       int* __restrict__ csr_src, float* __restrict__ csr_w, int e) {
    int i = blockIdx.x * 256 + threadIdx.x;
    if (i >= e) return;
    int s = src[i], d = dst[i];
    int pos = atomicAdd(&cursor[d], 1);
    csr_src[pos] = s;
    csr_w[pos] = dinv[s] * dinv[d];
}

// ---------------- Cheb SpMV, bf16 storage, paired features ----------------
// Tout[n,f] = -scale * sum_e w[e]*X[src[e],f]  - (Tprev ? Tprev[n,f] : 0)

template <int F, int TX>
__global__ void k_spmv2(const u16* __restrict__ X, const u16* __restrict__ Tprev,
                        u16* __restrict__ Tout, const int* __restrict__ row_ptr,
                        const int* __restrict__ csr_src, const float* __restrict__ csr_w,
                        int n, float scale) {
    constexpr int F2 = F / 2;
    int fp = threadIdx.x;
    int node = blockIdx.x * blockDim.y + threadIdx.y;
    if (node >= n) return;
    if (TX > F2 && fp >= F2) return;
    int lo = row_ptr[node], hi = row_ptr[node + 1];
    float a0 = 0.f, a1 = 0.f;
    for (int e = lo; e < hi; e++) {
        float w = csr_w[e];
        unsigned v = *(const unsigned*)(X + (size_t)csr_src[e] * F + 2 * fp);
        a0 = fmaf(w, __uint_as_float(v << 16), a0);
        a1 = fmaf(w, __uint_as_float(v & 0xffff0000u), a1);
    }
    float v0 = -scale * a0, v1 = -scale * a1;
    if (Tprev) {
        unsigned pv = *(const unsigned*)(Tprev + (size_t)node * F + 2 * fp);
        v0 -= __uint_as_float(pv << 16);
        v1 -= __uint_as_float(pv & 0xffff0000u);
    }
    unsigned outv = (unsigned)f2bf(v0) | ((unsigned)f2bf(v1) << 16);
    *(unsigned*)(Tout + (size_t)node * F + 2 * fp) = outv;
}

// ---------------- VALU chebgate (layers 0,1; tiny) ----------------
struct TP { const void* p[5]; };

template <typename ST, int FIN, int K>
__global__ __launch_bounds__(256) void k_chebgate(TP tp, const float* __restrict__ Wp,
                                                  const float* __restrict__ b4,
                                                  ST* __restrict__ H, int n, int F,
                                                  int F4pad) {
    __shared__ float As[FIN][68];
    __shared__ float Ws[FIN][128];
    const int tid = threadIdx.x;
    const int fx = tid & 31, ry = tid >> 5;
    const int row0 = blockIdx.y * 64;
    const int f0 = blockIdx.x * 32;
    const int f = f0 + fx;

    float acc[8][3];
    const float4 bv = *(const float4*)&b4[(size_t)f * 4];
#pragma unroll
    for (int r = 0; r < 8; r++) { acc[r][0] = bv.x; acc[r][1] = bv.y; acc[r][2] = bv.z; }

#pragma unroll
    for (int t = 0; t < K; t++) {
        const ST* T = (const ST*)tp.p[t];
        for (int idx = tid; idx < 64 * FIN; idx += 256) {
            int r = idx / FIN, a = idx - r * FIN;
            int rr = row0 + r;
            if (rr >= n) rr = n - 1;
            As[a][r] = ldv(&T[(size_t)rr * FIN + a]);
        }
        const float* Wt = Wp + (size_t)t * FIN * F4pad + (size_t)f0 * 4;
        for (int idx = tid; idx < FIN * 128; idx += 256) {
            int aa = idx >> 7, c = idx & 127;
            Ws[aa][c] = Wt[(size_t)aa * F4pad + c];
        }
        __syncthreads();
#pragma unroll 2
        for (int a = 0; a < FIN; a++) {
            const float4 w = *(const float4*)&Ws[a][fx * 4];
            const float4 x0 = *(const float4*)&As[a][ry * 8];
            const float4 x1 = *(const float4*)&As[a][ry * 8 + 4];
            const float xr[8] = {x0.x, x0.y, x0.z, x0.w, x1.x, x1.y, x1.z, x1.w};
#pragma unroll
            for (int r = 0; r < 8; r++) {
                acc[r][0] = fmaf(xr[r], w.x, acc[r][0]);
                acc[r][1] = fmaf(xr[r], w.y, acc[r][1]);
                acc[r][2] = fmaf(xr[r], w.z, acc[r][2]);
            }
        }
        __syncthreads();
    }

    if (f < F) {
#pragma unroll
        for (int r = 0; r < 8; r++) {
            int row = row0 + ry * 8 + r;
            if (row < n) {
                float gi = 1.f / (1.f + __expf(-acc[r][0]));
                float go = 1.f / (1.f + __expf(-acc[r][2]));
                float c = gi * tanhf(acc[r][1]);
                float h = go * tanhf(c);
                stv(&H[(size_t)row * F + f], fmaxf(h, 0.f));
            }
        }
    }
}

// ---------------- MFMA chebgate (layers 2,3) ----------------
// C[node][g,f] = sum_k A[node][k] * Wt[g*FPAD+f][k], k = (t*FIN + a).
// Block: 4 waves, each wave 32 rows x (2 f-subtiles x 3 gates).
// A-frag: lane m=l&15, k=(l>>4)*8+j  (16B global load, no LDS).
// B-frag: lane n=l&15, k=(l>>4)*8+j  (Wt stored [col][k], 16B load, L2-hot).
// C/D:    col=l&15, row=(l>>4)*4+reg.

template <int FIN, int K, int FPAD>
__global__ __launch_bounds__(256) void k_chebgate_mfma(TP tp, const u16* __restrict__ Wt,
                                                       const float* __restrict__ b3,
                                                       u16* __restrict__ H, int n, int F,
                                                       int Hstride) {
    constexpr int KT = K * FIN;
    const int wave = threadIdx.x >> 6;
    const int lane = threadIdx.x & 63;
    const int r0 = blockIdx.x * 128 + wave * 32;
    const int f0 = blockIdx.y * 32;
    const int ln = lane & 15;
    const int lk = lane >> 4;

    f32x4 acc[2][2][3];
#pragma unroll
    for (int rt = 0; rt < 2; rt++)
#pragma unroll
        for (int s = 0; s < 2; s++)
#pragma unroll
            for (int g = 0; g < 3; g++) acc[rt][s][g] = (f32x4){0.f, 0.f, 0.f, 0.f};

    int arow[2];
#pragma unroll
    for (int rt = 0; rt < 2; rt++) {
        int row = r0 + rt * 16 + ln;
        arow[rt] = row < n ? row : n - 1;
    }

    for (int k0 = 0; k0 < KT; k0 += 32) {
        const int t = k0 / FIN;
        const int a0 = k0 % FIN;
        const u16* T = (const u16*)tp.p[t];
        bf16x8 af[2];
#pragma unroll
        for (int rt = 0; rt < 2; rt++)
            af[rt] = *(const bf16x8*)(T + (size_t)arow[rt] * FIN + a0 + lk * 8);
#pragma unroll
        for (int s = 0; s < 2; s++) {
#pragma unroll
            for (int g = 0; g < 3; g++) {
                int col = g * FPAD + f0 + s * 16 + ln;
                bf16x8 bf = *(const bf16x8*)(Wt + (size_t)col * KT + k0 + lk * 8);
#pragma unroll
                for (int rt = 0; rt < 2; rt++)
                    acc[rt][s][g] = __builtin_amdgcn_mfma_f32_16x16x32_bf16(
                        af[rt], bf, acc[rt][s][g], 0, 0, 0);
            }
        }
    }

#pragma unroll
    for (int s = 0; s < 2; s++) {
        int fcol = f0 + s * 16 + ln;
        if (fcol >= F) continue;
        float bi = b3[0 * FPAD + fcol];
        float bc = b3[1 * FPAD + fcol];
        float bo = b3[2 * FPAD + fcol];
#pragma unroll
        for (int rt = 0; rt < 2; rt++) {
#pragma unroll
            for (int reg = 0; reg < 4; reg++) {
                int row = r0 + rt * 16 + lk * 4 + reg;
                if (row < n) {
                    float gi = 1.f / (1.f + __expf(-(acc[rt][s][0][reg] + bi)));
                    float go = 1.f / (1.f + __expf(-(acc[rt][s][2][reg] + bo)));
                    float c = gi * tanhf(acc[rt][s][1][reg] + bc);
                    float h = go * tanhf(c);
                    H[(size_t)row * Hstride + fcol] = f2bf(fmaxf(h, 0.f));
                }
            }
        }
    }
}

// ---------------- weight/bias packing ----------------
// VALU layers: Wp[(k*FIN+a)*F4pad + f*4 + g], fp32.
__global__ void k_pack_w(const float* __restrict__ Wi, const float* __restrict__ Wc,
                         const float* __restrict__ Wo, float* __restrict__ Wp,
                         int KFIN, int F, int F4pad) {
    int idx = blockIdx.x * 256 + threadIdx.x;
    int tot = KFIN * F4pad;
    if (idx >= tot) return;
    int c = idx % F4pad;
    int ka = idx / F4pad;
    int f = c >> 2, g = c & 3;
    float v = 0.f;
    if (g < 3 && f < F) {
        const float* Wg = (g == 0) ? Wi : ((g == 1) ? Wc : Wo);
        v = Wg[(size_t)ka * F + f];
    }
    Wp[idx] = v;
}

__global__ void k_pack_b(const float* __restrict__ bxi, const float* __restrict__ bhi,
                         const float* __restrict__ bi, const float* __restrict__ bxc,
                         const float* __restrict__ bhc, const float* __restrict__ bc,
                         const float* __restrict__ bxo, const float* __restrict__ bho,
                         const float* __restrict__ bo, float* __restrict__ b4,
                         int F, int F4pad) {
    int idx = blockIdx.x * 256 + threadIdx.x;
    if (idx >= F4pad) return;
    int f = idx >> 2, g = idx & 3;
    float v = 0.f;
    if (g < 3 && f < F) {
        if (g == 0) v = bxi[f] + bhi[f] + bi[f];
        else if (g == 1) v = bxc[f] + bhc[f] + bc[f];
        else v = bxo[f] + bho[f] + bo[f];
    }
    b4[idx] = v;
}

// MFMA layers: Wt[col][k] bf16, col = g*FPAD+f; b3[g*FPAD+f] fp32.
__global__ void k_pack_wt(const float* __restrict__ Wi, const float* __restrict__ Wc,
                          const float* __restrict__ Wo, u16* __restrict__ Wt,
                          int KT, int Fin, int F, int FPAD) {
    int idx = blockIdx.x * 256 + threadIdx.x;
    int tot = 3 * FPAD * KT;
    if (idx >= tot) return;
    int k = idx % KT;
    int col = idx / KT;
    int g = col / FPAD, f = col % FPAD;
    int t = k / Fin, a = k % Fin;
    float v = 0.f;
    if (f < F) {
        const float* Wg = (g == 0) ? Wi : ((g == 1) ? Wc : Wo);
        v = Wg[((size_t)t * Fin + a) * F + f];
    }
    Wt[idx] = f2bf(v);
}

__global__ void k_pack_b3(const float* __restrict__ bxi, const float* __restrict__ bhi,
                          const float* __restrict__ bi, const float* __restrict__ bxc,
                          const float* __restrict__ bhc, const float* __restrict__ bc,
                          const float* __restrict__ bxo, const float* __restrict__ bho,
                          const float* __restrict__ bo, float* __restrict__ b3,
                          int F, int FPAD) {
    int idx = blockIdx.x * 256 + threadIdx.x;
    if (idx >= 3 * FPAD) return;
    int g = idx / FPAD, f = idx % FPAD;
    float v = 0.f;
    if (f < F) {
        if (g == 0) v = bxi[f] + bhi[f] + bi[f];
        else if (g == 1) v = bxc[f] + bhc[f] + bc[f];
        else v = bxo[f] + bho[f] + bo[f];
    }
    b3[idx] = v;
}

// ---------------- fp32 -> bf16 input convert ----------------
__global__ void k_cvt(const float* __restrict__ x, u16* __restrict__ y, int n) {
    int i = blockIdx.x * 256 + threadIdx.x;
    if (i < n) y[i] = f2bf(x[i]);
}

// ---------------- final linear + softmax ----------------
__global__ void k_final(const u16* __restrict__ H, const float* __restrict__ W,
                        const float* __restrict__ b, float* __restrict__ out, int n) {
    int gtid = blockIdx.x * blockDim.x + threadIdx.x;
    int node = gtid >> 6;
    int lane = threadIdx.x & 63;
    if (node >= n) return;
    const u16* h = H + (size_t)node * 152;
    float l0 = 0.f, l1 = 0.f;
    for (int f = lane; f < 152; f += 64) {
        float hv = bf2f(h[f]);
        l0 = fmaf(hv, W[f * 2 + 0], l0);
        l1 = fmaf(hv, W[f * 2 + 1], l1);
    }
#pragma unroll
    for (int off = 32; off > 0; off >>= 1) {
        l0 += __shfl_down(l0, off);
        l1 += __shfl_down(l1, off);
    }
    if (lane == 0) {
        l0 += b[0];
        l1 += b[1];
        float m = fmaxf(l0, l1);
        float e0 = __expf(l0 - m), e1 = __expf(l1 - m);
        float s = 1.f / (e0 + e1);
        out[(size_t)node * 2 + 0] = e0 * s;
        out[(size_t)node * 2 + 1] = e1 * s;
    }
}

// ---------------- launch ----------------

static inline size_t al(size_t x) { return (x + 255) & ~(size_t)255; }

extern "C" void kernel_launch(void* const* d_in, const int* in_sizes, int n_in,
                              void* d_out, int out_size, void* d_ws, size_t ws_size,
                              hipStream_t stream) {
    const float* X0 = (const float*)d_in[0];
    const int* ei = (const int*)d_in[1];
    const int N = in_sizes[0] / IN_CH;
    const int E = in_sizes[1] / 2;
    const int* src = ei;
    const int* dst = ei + E;

    // ---- workspace carve (~122 MB) ----
    char* p = (char*)d_ws;
    size_t off = 0;
    auto carve = [&](size_t bytes) -> char* { char* r = p + off; off += al(bytes); return r; };
    int* row_ptr  = (int*)carve((size_t)(N + 1) * 4);
    int* cnt      = (int*)carve((size_t)N * 4);   // doubles as cursor
    float* dinv   = (float*)carve((size_t)N * 4);
    int* csr_src  = (int*)carve((size_t)E * 4);
    float* csr_w  = (float*)carve((size_t)E * 4);
    const size_t S64 = al((size_t)N * 64 * 2);    // one N x 64 bf16 buffer
    char* bufA    = carve(5 * S64);               // 64 MB
    char* bufB    = carve((size_t)N * 304);       // 30.4 MB
    float* Wp     = (float*)carve((size_t)48 * 128 * 4);
    float* b4     = (float*)carve((size_t)128 * 4);
    u16* Wt       = (u16*)carve((size_t)480 * 320 * 2);
    float* b3     = (float*)carve((size_t)480 * 4);
    (void)ws_size;  // total ~122 MB, under proven-fit bound

    // region overlays (see layer schedule for liveness)
    u16* X0c  = (u16*)bufA;                                   // N x 10
    u16* T0_1 = (u16*)(bufA + al((size_t)N * 20));            // N x 10
    u16* H0   = (u16*)(bufA + S64);                           // N x 16 (L1 t0)
    u16* T1_1 = (u16*)(bufA + S64 + al((size_t)N * 32));      // N x 16
    u16* T1_2 = (u16*)(bufA + S64 + 2 * al((size_t)N * 32));  // N x 16
    u16* L2T[4];                                              // N x 32 each, in bufB
    for (int t = 0; t < 4; t++) L2T[t] = (u16*)(bufB + t * al((size_t)N * 64));
    u16* L3T[5];                                              // N x 64 each, in bufA
    for (int t = 0; t < 5; t++) L3T[t] = (u16*)(bufA + t * S64);
    u16* Hfin = (u16*)bufB;                                   // N x 152

    // ---- graph preprocessing ----
    int gE = (E + 255) / 256, gN = (N + 255) / 256;
    hipMemsetAsync(cnt, 0, (size_t)N * 4, stream);
    k_count<<<gE, 256, 0, stream>>>(dst, cnt, E);
    k_dinv<<<gN, 256, 0, stream>>>(cnt, dinv, N);
    k_scan<<<1, 1024, 0, stream>>>(cnt, row_ptr, N);
    k_copy_i32<<<gN, 256, 0, stream>>>(row_ptr, cnt, N);
    k_fill<<<gE, 256, 0, stream>>>(src, dst, dinv, cnt, csr_src, csr_w, E);

    k_cvt<<<(N * IN_CH + 255) / 256, 256, 0, stream>>>(X0, X0c, N * IN_CH);

    dim3 gv(1, (N + 63) / 64);
    int rb = (N + 127) / 128;

    // ---- layer 0: VALU, K=2, Fin=10, F=16 (base 2) ----
    {
        k_pack_w<<<(20 * 128 + 255) / 256, 256, 0, stream>>>(
            (const float*)d_in[2], (const float*)d_in[10], (const float*)d_in[14], Wp, 20, 16, 128);
        k_pack_b<<<1, 256, 0, stream>>>(
            (const float*)d_in[3], (const float*)d_in[4], (const float*)d_in[5],
            (const float*)d_in[11], (const float*)d_in[12], (const float*)d_in[13],
            (const float*)d_in[15], (const float*)d_in[16], (const float*)d_in[17], b4, 16, 128);
        dim3 bs(8, 32);
        k_spmv2<10, 8><<<(N + 31) / 32, bs, 0, stream>>>(X0c, nullptr, T0_1, row_ptr, csr_src, csr_w, N, 1.f);
        TP tp; tp.p[0] = X0c; tp.p[1] = T0_1;
        k_chebgate<u16, 10, 2><<<gv, 256, 0, stream>>>(tp, Wp, b4, H0, N, 16, 128);
    }
    // ---- layer 1: VALU, K=3, Fin=16, F=32 (base 18) ----
    {
        k_pack_w<<<(48 * 128 + 255) / 256, 256, 0, stream>>>(
            (const float*)d_in[18], (const float*)d_in[26], (const float*)d_in[30], Wp, 48, 32, 128);
        k_pack_b<<<1, 256, 0, stream>>>(
            (const float*)d_in[19], (const float*)d_in[20], (const float*)d_in[21],
            (const float*)d_in[27], (const float*)d_in[28], (const float*)d_in[29],
            (const float*)d_in[31], (const float*)d_in[32], (const float*)d_in[33], b4, 32, 128);
        dim3 bs(8, 32);
        k_spmv2<16, 8><<<(N + 31) / 32, bs, 0, stream>>>(H0, nullptr, T1_1, row_ptr, csr_src, csr_w, N, 1.f);
        k_spmv2<16, 8><<<(N + 31) / 32, bs, 0, stream>>>(T1_1, H0, T1_2, row_ptr, csr_src, csr_w, N, 2.f);
        TP tp; tp.p[0] = H0; tp.p[1] = T1_1; tp.p[2] = T1_2;
        k_chebgate<u16, 16, 3><<<gv, 256, 0, stream>>>(tp, Wp, b4, L2T[0], N, 32, 128);
    }
    // ---- layer 2: MFMA, K=4, Fin=32, F=64, FPAD=64 (base 34) ----
    {
        k_pack_wt<<<(3 * 64 * 128 + 255) / 256, 256, 0, stream>>>(
            (const float*)d_in[34], (const float*)d_in[42], (const float*)d_in[46], Wt, 128, 32, 64, 64);
        k_pack_b3<<<1, 256, 0, stream>>>(
            (const float*)d_in[35], (const float*)d_in[36], (const float*)d_in[37],
            (const float*)d_in[43], (const float*)d_in[44], (const float*)d_in[45],
            (const float*)d_in[47], (const float*)d_in[48], (const float*)d_in[49], b3, 64, 64);
        dim3 bs(16, 16);
        k_spmv2<32, 16><<<(N + 15) / 16, bs, 0, stream>>>(L2T[0], nullptr, L2T[1], row_ptr, csr_src, csr_w, N, 1.f);
        k_spmv2<32, 16><<<(N + 15) / 16, bs, 0, stream>>>(L2T[1], L2T[0], L2T[2], row_ptr, csr_src, csr_w, N, 2.f);
        k_spmv2<32, 16><<<(N + 15) / 16, bs, 0, stream>>>(L2T[2], L2T[1], L2T[3], row_ptr, csr_src, csr_w, N, 2.f);
        TP tp; for (int t = 0; t < 4; t++) tp.p[t] = L2T[t];
        k_chebgate_mfma<32, 4, 64><<<dim3(rb, 2), 256, 0, stream>>>(tp, Wt, b3, L3T[0], N, 64, 64);
    }
    // ---- layer 3: MFMA, K=5, Fin=64, F=152, FPAD=160 (base 50) ----
    {
        k_pack_wt<<<(3 * 160 * 320 + 255) / 256, 256, 0, stream>>>(
            (const float*)d_in[50], (const float*)d_in[58], (const float*)d_in[62], Wt, 320, 64, 152, 160);
        k_pack_b3<<<2, 256, 0, stream>>>(
            (const float*)d_in[51], (const float*)d_in[52], (const float*)d_in[53],
            (const float*)d_in[59], (const float*)d_in[60], (const float*)d_in[61],
            (const float*)d_in[63], (const float*)d_in[64], (const float*)d_in[65], b3, 152, 160);
        dim3 bs(32, 8);
        k_spmv2<64, 32><<<(N + 7) / 8, bs, 0, stream>>>(L3T[0], nullptr, L3T[1], row_ptr, csr_src, csr_w, N, 1.f);
        k_spmv2<64, 32><<<(N + 7) / 8, bs, 0, stream>>>(L3T[1], L3T[0], L3T[2], row_ptr, csr_src, csr_w, N, 2.f);
        k_spmv2<64, 32><<<(N + 7) / 8, bs, 0, stream>>>(L3T[2], L3T[1], L3T[3], row_ptr, csr_src, csr_w, N, 2.f);
        k_spmv2<64, 32><<<(N + 7) / 8, bs, 0, stream>>>(L3T[3], L3T[2], L3T[4], row_ptr, csr_src, csr_w, N, 2.f);
        TP tp; for (int t = 0; t < 5; t++) tp.p[t] = L3T[t];
        k_chebgate_mfma<64, 5, 160><<<dim3(rb, 5), 256, 0, stream>>>(tp, Wt, b3, Hfin, N, 152, 152);
    }

    k_final<<<(N * 64 + 255) / 256, 256, 0, stream>>>(Hfin, (const float*)d_in[66],
                                                      (const float*)d_in[67], (float*)d_out, N);
}